// Round 4
// baseline (5742.796 us; speedup 1.0000x reference)
//
#include <hip/hip_runtime.h>
#include <math.h>

typedef unsigned int u32;
typedef unsigned long long u64;

#define BATCH 64
#define A_TOT 8649
#define TOPN  6000
#define POST  1500
#define NB    4096
#define NTP   512           // prep kernel threads
#define NTN   256           // nms kernel threads (4 waves -> 1 wave/EU)
#define NWAVE 4
#define NSLOT 24
#define KEY_STRIDE 8704
#define QTOT  6144          // NWAVE * NSLOT * 64 slots (>= TOPN)
#define SENT_T 0x3FFFFFFF

// ---- DPP full-wave reductions: result valid in lane 63 ----
__device__ __forceinline__ int wave_min_dpp(int v) {
    int t;
    t = __builtin_amdgcn_update_dpp(v, v, 0x111, 0xf, 0xf, false); v = min(v, t); // row_shr:1
    t = __builtin_amdgcn_update_dpp(v, v, 0x112, 0xf, 0xf, false); v = min(v, t); // row_shr:2
    t = __builtin_amdgcn_update_dpp(v, v, 0x114, 0xf, 0xe, false); v = min(v, t); // row_shr:4
    t = __builtin_amdgcn_update_dpp(v, v, 0x118, 0xf, 0xc, false); v = min(v, t); // row_shr:8
    t = __builtin_amdgcn_update_dpp(v, v, 0x142, 0xa, 0xf, false); v = min(v, t); // row_bcast:15
    t = __builtin_amdgcn_update_dpp(v, v, 0x143, 0xc, 0xf, false); v = min(v, t); // row_bcast:31
    return v;
}
__device__ __forceinline__ int wave_max_dpp(int v) {
    int t;
    t = __builtin_amdgcn_update_dpp(v, v, 0x111, 0xf, 0xf, false); v = max(v, t);
    t = __builtin_amdgcn_update_dpp(v, v, 0x112, 0xf, 0xf, false); v = max(v, t);
    t = __builtin_amdgcn_update_dpp(v, v, 0x114, 0xf, 0xe, false); v = max(v, t);
    t = __builtin_amdgcn_update_dpp(v, v, 0x118, 0xf, 0xc, false); v = max(v, t);
    t = __builtin_amdgcn_update_dpp(v, v, 0x142, 0xa, 0xf, false); v = max(v, t);
    t = __builtin_amdgcn_update_dpp(v, v, 0x143, 0xc, 0xf, false); v = max(v, t);
    return v;
}

// ======================= PREP: sort + decode + area-order =======================
__global__ __launch_bounds__(NTP) void prep_kernel(
    const float* __restrict__ deltas,    // [B, A, 4]
    const float* __restrict__ probs,     // [B, A]
    const float* __restrict__ anchors,   // [A, 4]
    u64*   __restrict__ wskeys,          // [B, KEY_STRIDE]
    float4* __restrict__ wsboxes,        // [B, QTOT] rank-indexed decoded boxes
    u32*   __restrict__ wsaorder)        // [B, QTOT] area-order -> rank
{
    #pragma clang fp contract(off)
    __shared__ __align__(16) u32 lds_pool[2*NB];
    __shared__ u32 stemp[2*NTP];
    u32* bucketA = lds_pool;
    u32* bucketB = lds_pool + NB;

    const int tid = threadIdx.x;
    const int b   = blockIdx.x;
    const float* pb = probs + (size_t)b * A_TOT;
    u64*    keys    = wskeys   + (size_t)b * KEY_STRIDE;
    float4* boxws_b = wsboxes  + (size_t)b * QTOT;
    u32*    aorder  = wsaorder + (size_t)b * QTOT;

    // ---- Phase A: stable descending score sort ----
    for (int i = tid; i < NB; i += NTP) bucketA[i] = 0u;
    __syncthreads();
    for (int j = tid; j < A_TOT; j += NTP) {
        float s = pb[j];
        int bkt = (int)(s * (float)NB);
        bkt = (NB-1) - min(max(bkt, 0), NB-1);
        atomicAdd(&bucketA[bkt], 1u);
    }
    __syncthreads();
    {   // exclusive scan, 8 counts/thread + Hillis-Steele over 512
        int base = tid << 3;
        u32 c[8]; u32 mysum = 0;
        #pragma unroll
        for (int i = 0; i < 8; ++i) { c[i] = bucketA[base+i]; mysum += c[i]; }
        stemp[tid] = mysum;
        __syncthreads();
        int src = 0;
        for (int off = 1; off < NTP; off <<= 1) {
            u32 v = stemp[src*NTP + tid];
            if (tid >= off) v += stemp[src*NTP + tid - off];
            stemp[(src^1)*NTP + tid] = v;
            __syncthreads();
            src ^= 1;
        }
        u32 run = stemp[src*NTP + tid] - mysum;
        #pragma unroll
        for (int i = 0; i < 8; ++i) { bucketA[base+i] = run; bucketB[base+i] = run; run += c[i]; }
    }
    __syncthreads();
    for (int j = tid; j < A_TOT; j += NTP) {
        float s = pb[j];
        int bkt = (int)(s * (float)NB);
        bkt = (NB-1) - min(max(bkt, 0), NB-1);
        u32 pos = atomicAdd(&bucketB[bkt], 1u);
        keys[pos] = ((u64)__float_as_uint(s) << 32) | (u64)(~(u32)j);
    }
    __syncthreads();
    for (int bkt = tid; bkt < NB; bkt += NTP) {   // per-bucket insertion sort
        int begin = (int)bucketA[bkt], end = (int)bucketB[bkt];
        for (int k = begin + 1; k < end; ++k) {
            u64 key = keys[k];
            int m = k - 1;
            while (m >= begin && keys[m] < key) { keys[m+1] = keys[m]; --m; }
            keys[m+1] = key;
        }
    }
    __syncthreads();

    // ---- Phase B: decode rank-order boxes + area histogram ----
    for (int i = tid; i < NB; i += NTP) bucketA[i] = 0u;
    __syncthreads();
    for (int k = 0; k < QTOT/NTP; ++k) {
        int r = tid + k*NTP;
        if (r < TOPN) {
            u64 kk = keys[r];
            u32 aidx = ~((u32)kk);
            float4 av = *(const float4*)(anchors + (size_t)aidx*4);
            float4 dv = *(const float4*)(deltas + ((size_t)b*A_TOT + aidx)*4);
            float d0 = dv.x*0.1f, d1 = dv.y*0.1f, d2 = dv.z*0.2f, d3 = dv.w*0.2f;
            float ah = av.z - av.x, aw = av.w - av.y;
            float acy = av.x + 0.5f*ah, acx = av.y + 0.5f*aw;
            float h  = (float)exp((double)d2) * ah;   // correctly-rounded fp32 exp
            float w_ = (float)exp((double)d3) * aw;
            float cy = d0*ah + acy;
            float cx = d1*aw + acx;
            float y1 = cy - 0.5f*h, x1 = cx - 0.5f*w_;
            float y2 = cy + 0.5f*h, x2 = cx + 0.5f*w_;
            boxws_b[r] = make_float4(y1, x1, y2, x2);
            float area = (y2 - y1) * (x2 - x1);
            int ab = (int)(area * 1024.0f);
            ab = min(max(ab, 0), NB-1);
            atomicAdd(&bucketA[ab], 1u);
            keys[r] = (kk & 0xFFFFFFFF00000000ull) | (u64)(u32)ab;  // stash bucket
        }
    }
    __syncthreads();
    {   // scan area counts -> cursors in bucketB
        int base = tid << 3;
        u32 c[8]; u32 mysum = 0;
        #pragma unroll
        for (int i = 0; i < 8; ++i) { c[i] = bucketA[base+i]; mysum += c[i]; }
        stemp[tid] = mysum;
        __syncthreads();
        int src = 0;
        for (int off = 1; off < NTP; off <<= 1) {
            u32 v = stemp[src*NTP + tid];
            if (tid >= off) v += stemp[src*NTP + tid - off];
            stemp[(src^1)*NTP + tid] = v;
            __syncthreads();
            src ^= 1;
        }
        u32 run = stemp[src*NTP + tid] - mysum;
        #pragma unroll
        for (int i = 0; i < 8; ++i) { bucketB[base+i] = run; run += c[i]; }
    }
    __syncthreads();
    // ---- Phase C: area-order scatter ----
    for (int q = TOPN + tid; q < QTOT; q += NTP) aorder[q] = 0xFFFFFFFFu;
    for (int k = 0; k < QTOT/NTP; ++k) {
        int r = tid + k*NTP;
        if (r < TOPN) {
            int ab = (int)(keys[r] & (u64)(NB-1));
            u32 pos = atomicAdd(&bucketB[ab], 1u);
            aorder[pos] = (u32)r;
        }
    }
}

// ======================= NMS: register-resident pick loop =======================
// rr encoding: (rank << 7) | (slot << 2) | wave   (rank<8192, slot<32, wave<4)
#define DECL_SLOT(i) float y1_##i, x1_##i, y2_##i, x2_##i, ar_##i; u32 rr_##i;

#define LOAD_SLOT(i) { \
    int q = wv*(NSLOT*64) + (i)*64 + ln; \
    u32 r = aorder[q]; \
    if (r != 0xFFFFFFFFu) { \
        float4 bx = boxws_b[r]; \
        y1_##i = bx.x; x1_##i = bx.y; y2_##i = bx.z; x2_##i = bx.w; \
        float a_ = (bx.z - bx.x) * (bx.w - bx.y); \
        ar_##i = a_; \
        rr_##i = (r << 7) | ((u32)(i) << 2) | (u32)wv; \
        mask |= 1u << (i); \
        aminb = min(aminb, __float_as_uint(a_)); \
        amaxb = max(amaxb, __float_as_uint(a_)); \
    } else { \
        y1_##i=x1_##i=y2_##i=x2_##i=ar_##i=0.f; rr_##i = (u32)SENT_T; \
    } }

#define TEST_SLOT(i) if (mask & (1u << (i))) { \
    float bA = ar_##i; \
    if (bA >= loA && bA <= hiA) { \
        float yy1 = fmaxf(sy1, y1_##i); \
        float xx1 = fmaxf(sx1, x1_##i); \
        float yy2 = fminf(sy2, y2_##i); \
        float xx2 = fminf(sx2, x2_##i); \
        float iy = fmaxf(yy2 - yy1, 0.0f); \
        float ix = fmaxf(xx2 - xx1, 0.0f); \
        float inter = iy * ix; \
        float den = ((sA + bA) - inter) + 1e-9f; \
        bool sup; \
        if      (inter > 0.7002f * den) sup = true; \
        else if (inter < 0.6998f * den) sup = false; \
        else sup = (inter / den > 0.7f); \
        if (sup) { mask &= ~(1u << (i)); changed = true; } \
    } }

#define MIN_SLOT(i) if ((mask & (1u << (i))) && rr_##i < t_) { \
    t_ = rr_##i; cby1 = y1_##i; cbx1 = x1_##i; cby2 = y2_##i; cbx2 = x2_##i; }

#define FORALL(M) M(0) M(1) M(2) M(3) M(4) M(5) M(6) M(7) M(8) M(9) M(10) M(11) \
    M(12) M(13) M(14) M(15) M(16) M(17) M(18) M(19) M(20) M(21) M(22) M(23)

__global__ __launch_bounds__(NTN)
__attribute__((amdgpu_waves_per_eu(1, 1)))   // budget = 512 VGPR: stop the spill
void nms_kernel(
    float* __restrict__ out,
    const u64*   __restrict__ wskeys,
    const float4* __restrict__ wsboxes,
    const u32*   __restrict__ wsaorder)
{
    #pragma clang fp contract(off)
    __shared__ u32 pickrank[POST];
    __shared__ __align__(16) u32 wkey[2][4];
    __shared__ __align__(16) float4 wbox[2][4];

    const int tid = threadIdx.x;
    const int b   = blockIdx.x;
    const int wv  = tid >> 6;
    const int ln  = tid & 63;
    const u64*    keys    = wskeys   + (size_t)b * KEY_STRIDE;
    const float4* boxws_b = wsboxes  + (size_t)b * QTOT;
    const u32*    aorder  = wsaorder + (size_t)b * QTOT;

    DECL_SLOT(0) DECL_SLOT(1) DECL_SLOT(2) DECL_SLOT(3) DECL_SLOT(4) DECL_SLOT(5)
    DECL_SLOT(6) DECL_SLOT(7) DECL_SLOT(8) DECL_SLOT(9) DECL_SLOT(10) DECL_SLOT(11)
    DECL_SLOT(12) DECL_SLOT(13) DECL_SLOT(14) DECL_SLOT(15) DECL_SLOT(16) DECL_SLOT(17)
    DECL_SLOT(18) DECL_SLOT(19) DECL_SLOT(20) DECL_SLOT(21) DECL_SLOT(22) DECL_SLOT(23)
    u32 mask = 0;
    u32 aminb = 0x7F800000u, amaxb = 0u;
    FORALL(LOAD_SLOT)
    float wMinA = __uint_as_float((u32)__builtin_amdgcn_readlane(wave_min_dpp((int)aminb), 63));
    float wMaxA = __uint_as_float((u32)__builtin_amdgcn_readlane(wave_max_dpp((int)amaxb), 63));

    u32 tmin; float cby1 = 0.f, cbx1 = 0.f, cby2 = 0.f, cbx2 = 0.f;
    {
        u32 t_ = (u32)SENT_T;
        FORALL(MIN_SLOT)
        tmin = t_;
    }
    {
        u32 wmin = (u32)__builtin_amdgcn_readlane(wave_min_dpp((int)tmin), 63);
        if (ln == 63) wkey[0][wv] = wmin;
        if (tmin == wmin && tmin != (u32)SENT_T)
            wbox[0][wv] = make_float4(cby1, cbx1, cby2, cbx2);
    }
    __syncthreads();

    int par = 0;
    int pend = POST;
    for (int p = 0; p < POST; ++p) {
        uint4 s0 = *((const uint4*)&wkey[par][0]);
        float4 b0 = wbox[par][0], b1 = wbox[par][1],    // speculative parallel reads:
               b2 = wbox[par][2], b3 = wbox[par][3];    // no dependent LDS hop
        u32 v = min(min(s0.x, s0.y), min(s0.z, s0.w));
        u32 vu = (u32)__builtin_amdgcn_readfirstlane((int)v);
        if (vu == (u32)SENT_T) { pend = p; break; }
        if (tid == 0) pickrank[p] = vu >> 7;
        u32 wid = vu & 3u;                               // wave-uniform select
        float4 sb = (wid == 0) ? b0 : (wid == 1) ? b1 : (wid == 2) ? b2 : b3;
        float sy1 = sb.x, sx1 = sb.y, sy2 = sb.z, sx2 = sb.w;
        float sA  = (sy2 - sy1) * (sx2 - sx1);
        float loA = 0.699f  * sA;
        float hiA = 1.4307f * sA;
        bool changed = false;
        if (tmin == vu) {                     // I own the pick: retire it
            mask &= ~(1u << ((vu >> 2) & 31u));
            changed = true;
        }
        if (!(wMaxA < loA || wMinA > hiA)) {  // wave-level area quick-reject
            FORALL(TEST_SLOT)
        }
        if (changed) {
            u32 t_ = (u32)SENT_T;
            FORALL(MIN_SLOT)
            tmin = t_;
        }
        u32 wmin = (u32)__builtin_amdgcn_readlane(wave_min_dpp((int)tmin), 63);
        if (ln == 63) wkey[par ^ 1][wv] = wmin;
        if (tmin == wmin && tmin != (u32)SENT_T)
            wbox[par ^ 1][wv] = make_float4(cby1, cbx1, cby2, cbx2);
        __syncthreads();
        par ^= 1;
    }
    __syncthreads();

    // ---- epilogue: parallel coalesced output ----
    const size_t sbase = (size_t)BATCH * POST * 4;
    float4* out4 = (float4*)out;
    for (int p = tid; p < POST; p += NTN) {
        size_t row = (size_t)b * POST + p;
        if (p < pend) {
            u32 r = pickrank[p];
            float4 bx = boxws_b[r];
            float4 ob;
            ob.x = fminf(fmaxf(bx.x, 0.f), 1.f);
            ob.y = fminf(fmaxf(bx.y, 0.f), 1.f);
            ob.z = fminf(fmaxf(bx.z, 0.f), 1.f);
            ob.w = fminf(fmaxf(bx.w, 0.f), 1.f);
            out4[row] = ob;
            out[sbase + row] = __uint_as_float((u32)(keys[r] >> 32));
        } else {
            out4[row] = make_float4(0.f, 0.f, 0.f, 0.f);
            out[sbase + row] = 0.f;
        }
    }
}

extern "C" void kernel_launch(void* const* d_in, const int* in_sizes, int n_in,
                              void* d_out, int out_size, void* d_ws, size_t ws_size,
                              hipStream_t stream) {
    const float* deltas  = (const float*)d_in[0];  // [64,31,31,36] f32
    const float* probs   = (const float*)d_in[1];  // [64,31,31,9]  f32
    // d_in[2] = gt_labels (unused)
    const float* anchors = (const float*)d_in[3];  // [8649,4] f32
    float* out = (float*)d_out;                    // 480000 f32

    char* ws = (char*)d_ws;
    u64*    wskeys   = (u64*)ws;                                    // 4,456,448 B
    float4* wsboxes  = (float4*)(ws + (size_t)BATCH*KEY_STRIDE*8);  // 6,291,456 B
    u32*    wsaorder = (u32*)(ws + (size_t)BATCH*KEY_STRIDE*8
                                 + (size_t)BATCH*QTOT*16);          // 1,572,864 B

    prep_kernel<<<dim3(BATCH), dim3(NTP), 0, stream>>>(
        deltas, probs, anchors, wskeys, wsboxes, wsaorder);
    nms_kernel<<<dim3(BATCH), dim3(NTN), 0, stream>>>(
        out, wskeys, wsboxes, wsaorder);
}

// Round 5
// 3608.042 us; speedup vs baseline: 1.5917x; 1.5917x over previous
//
#include <hip/hip_runtime.h>
#include <math.h>

typedef unsigned int u32;
typedef unsigned long long u64;

#define BATCH 64
#define A_TOT 8649
#define TOPN  6000
#define POST  1500
#define NB    4096
#define NT    512
#define NSLOT 12
#define KEY_STRIDE 8704
#define RSPACE 6144          // rank space (NSLOT * NT)
#define NW64   96            // RSPACE / 64 mask words
// dynamic LDS: boxes[6144]*16 + mask u32[192] + pickrank u32[1500]
#define DYN_LDS (98304 + 768 + 6000)

// Per-thread state is TINY by design: 12 area scalars + one bitmask. Ranks are
// computable (tid + i*NT). Boxes live in LDS. R1-R4 post-mortems: the register
// allocator never made large per-thread box state resident (VGPR 32/48/64/132
// vs >=144 needed) -> serial pick loop paid scratch latency every iteration.
#define DECL_S(i)  float ar_##i = 0.f;

#define DECODE_S(i) { \
    int r = tid + (i)*NT; \
    if (r < TOPN) { \
        u64 kk = keys[r]; \
        u32 aidx = ~((u32)kk); \
        float4 av = *(const float4*)(anchors + (size_t)aidx*4); \
        float4 dv = *(const float4*)(deltas + ((size_t)b*A_TOT + aidx)*4); \
        float d0 = dv.x*0.1f, d1 = dv.y*0.1f, d2 = dv.z*0.2f, d3 = dv.w*0.2f; \
        float ah = av.z - av.x, aw = av.w - av.y; \
        float acy = av.x + 0.5f*ah, acx = av.y + 0.5f*aw; \
        float h  = (float)exp((double)d2) * ah;   /* correctly-rounded fp32 exp */ \
        float w_ = (float)exp((double)d3) * aw; \
        float cy = d0*ah + acy; \
        float cx = d1*aw + acx; \
        float y1 = cy - 0.5f*h, x1 = cx - 0.5f*w_; \
        float y2 = cy + 0.5f*h, x2 = cx + 0.5f*w_; \
        boxes[r] = make_float4(y1, x1, y2, x2); \
        ar_##i = (y2 - y1) * (x2 - x1); \
        amask |= 1u << (i); \
    } }

// Suppression test for one slot. All global bit-clears are at ranks > rpick
// (locally-active => bit set => rank >= cursor, and first-set-bit is rpick);
// the picked rank is retired locally only (cursor jumps past its stale bit),
// so concurrent scanners in the same round cannot diverge -> 1 barrier/pick.
#define TEST_S(i) if (amask & (1u << (i))) { \
    int rk = tid + (i)*NT; \
    if (rk == rpick) { \
        amask &= ~(1u << (i)); \
    } else { \
        float bA = ar_##i; \
        if (bA >= loA && bA <= hiA) { \
            float4 bx = boxes[rk]; \
            float yy1 = fmaxf(sy1, bx.x); \
            float xx1 = fmaxf(sx1, bx.y); \
            float yy2 = fminf(sy2, bx.z); \
            float xx2 = fminf(sx2, bx.w); \
            float iy = fmaxf(yy2 - yy1, 0.0f); \
            float ix = fmaxf(xx2 - xx1, 0.0f); \
            float inter = iy * ix; \
            float den = ((sA + bA) - inter) + 1e-9f;  /* exact ref order */ \
            bool sup; \
            if      (inter > 0.7002f * den) sup = true; \
            else if (inter < 0.6998f * den) sup = false; \
            else sup = (inter / den > 0.7f); \
            if (sup) { \
                amask &= ~(1u << (i)); \
                atomicAnd(&mwords[rk >> 5], ~(1u << (rk & 31))); \
            } \
        } \
    } }

#define FORALL(M) M(0) M(1) M(2) M(3) M(4) M(5) M(6) M(7) M(8) M(9) M(10) M(11)

__global__ __launch_bounds__(NT) void roibbox_kernel(
    const float* __restrict__ deltas,    // [B, A, 4]
    const float* __restrict__ probs,     // [B, A]
    const float* __restrict__ anchors,   // [A, 4]
    float* __restrict__ out,             // [B*POST*4] boxes then [B*POST] scores
    u64*   __restrict__ wskeys)          // [B, KEY_STRIDE]
{
    #pragma clang fp contract(off)
    extern __shared__ __align__(16) char pool[];
    float4* boxes    = (float4*)pool;                     // [RSPACE] rank-indexed
    u32*    mwords   = (u32*)(pool + 98304);              // [192] active bitmask
    u64*    mwords64 = (u64*)mwords;                      // [96]
    u32*    pickrank = (u32*)(pool + 98304 + 768);        // [POST]
    // overlay (dead after sort): counting-sort buckets + scan temp (36 KB < 96 KB)
    u32* bucketA = (u32*)pool;
    u32* bucketB = bucketA + NB;
    u32* stemp   = bucketB + NB;                          // [2*NT]

    const int tid = threadIdx.x;
    const int b   = blockIdx.x;
    const int ln  = tid & 63;
    const float* pb = probs + (size_t)b * A_TOT;
    u64* keys = wskeys + (size_t)b * KEY_STRIDE;

    // ================= Phase A: stable descending score sort =================
    // key = score_bits<<32 | ~idx  -> exact lax.top_k tie semantics
    for (int i = tid; i < NB; i += NT) bucketA[i] = 0u;
    __syncthreads();
    for (int j = tid; j < A_TOT; j += NT) {
        float s = pb[j];
        int bkt = (int)(s * (float)NB);
        bkt = (NB-1) - min(max(bkt, 0), NB-1);
        atomicAdd(&bucketA[bkt], 1u);
    }
    __syncthreads();
    {   // exclusive scan, 8 counts/thread + Hillis-Steele over 512
        int base = tid << 3;
        u32 c[8]; u32 mysum = 0;
        #pragma unroll
        for (int i = 0; i < 8; ++i) { c[i] = bucketA[base+i]; mysum += c[i]; }
        stemp[tid] = mysum;
        __syncthreads();
        int src = 0;
        for (int off = 1; off < NT; off <<= 1) {
            u32 v = stemp[src*NT + tid];
            if (tid >= off) v += stemp[src*NT + tid - off];
            stemp[(src^1)*NT + tid] = v;
            __syncthreads();
            src ^= 1;
        }
        u32 run = stemp[src*NT + tid] - mysum;
        #pragma unroll
        for (int i = 0; i < 8; ++i) { bucketA[base+i] = run; bucketB[base+i] = run; run += c[i]; }
    }
    __syncthreads();
    for (int j = tid; j < A_TOT; j += NT) {
        float s = pb[j];
        int bkt = (int)(s * (float)NB);
        bkt = (NB-1) - min(max(bkt, 0), NB-1);
        u32 pos = atomicAdd(&bucketB[bkt], 1u);
        keys[pos] = ((u64)__float_as_uint(s) << 32) | (u64)(~(u32)j);
    }
    __syncthreads();
    for (int bkt = tid; bkt < NB; bkt += NT) {   // per-bucket insertion sort
        int begin = (int)bucketA[bkt], end = (int)bucketB[bkt];
        for (int k = begin + 1; k < end; ++k) {
            u64 key = keys[k];
            int m = k - 1;
            while (m >= begin && keys[m] < key) { keys[m+1] = keys[m]; --m; }
            keys[m+1] = key;
        }
    }
    __syncthreads();   // buckets dead; LDS pool becomes the box store

    // ====== Phase B: decode my 12 ranks into LDS boxes + register areas ======
    DECL_S(0) DECL_S(1) DECL_S(2) DECL_S(3) DECL_S(4) DECL_S(5)
    DECL_S(6) DECL_S(7) DECL_S(8) DECL_S(9) DECL_S(10) DECL_S(11)
    u32 amask = 0;
    FORALL(DECODE_S)
    // active bitmask init: ranks 0..5999 set (187 full words + 16 bits)
    for (int i = tid; i < 192; i += NT)
        mwords[i] = (i < 187) ? 0xFFFFFFFFu : ((i == 187) ? 0xFFFFu : 0u);
    __syncthreads();

    // ====== Phase C: greedy NMS — first-set-bit pick, 1 barrier/pick ======
    int cursor = 0;
    int pend = POST;
    for (int p = 0; p < POST; ++p) {
        // scan for first active rank >= cursor (identical in every wave)
        int rpick = -1;
        int cw = cursor >> 6;
        u64 lowmask = (~0ull) << (cursor & 63);
        while (cw < NW64) {
            int widx = cw + ln;
            u64 w = (widx < NW64) ? mwords64[widx] : 0ull;
            if (widx == (cursor >> 6)) w &= lowmask;
            u64 bal = __ballot(w != 0ull);
            if (bal) {
                int l = __ffsll((unsigned long long)bal) - 1;
                u32 wlo = (u32)__shfl((int)(u32)w, l, 64);
                u32 whi = (u32)__shfl((int)(u32)(w >> 32), l, 64);
                u64 ww = ((u64)whi << 32) | (u64)wlo;
                rpick = (cw + l)*64 + (__ffsll((unsigned long long)ww) - 1);
                break;
            }
            cw += 64;
        }
        if (rpick < 0) { pend = p; break; }
        if (tid == 0) pickrank[p] = (u32)rpick;
        float4 sb = boxes[rpick];                 // LDS broadcast (uniform addr)
        float sy1 = sb.x, sx1 = sb.y, sy2 = sb.z, sx2 = sb.w;
        float sA  = (sy2 - sy1) * (sx2 - sx1);
        // area gate: iou <= min(A)/max(A); margins can't flip a ref decision
        float loA = 0.699f  * sA;
        float hiA = 1.4307f * sA;
        FORALL(TEST_S)
        cursor = rpick + 1;
        __syncthreads();
    }
    __syncthreads();

    // ====== epilogue: parallel coalesced output ======
    const size_t sbase = (size_t)BATCH * POST * 4;
    float4* out4 = (float4*)out;
    for (int p = tid; p < POST; p += NT) {
        size_t row = (size_t)b * POST + p;
        if (p < pend) {
            u32 r = pickrank[p];
            float4 bx = boxes[r];
            float4 ob;
            ob.x = fminf(fmaxf(bx.x, 0.f), 1.f);
            ob.y = fminf(fmaxf(bx.y, 0.f), 1.f);
            ob.z = fminf(fmaxf(bx.z, 0.f), 1.f);
            ob.w = fminf(fmaxf(bx.w, 0.f), 1.f);
            out4[row] = ob;
            out[sbase + row] = __uint_as_float((u32)(keys[r] >> 32));
        } else {
            out4[row] = make_float4(0.f, 0.f, 0.f, 0.f);
            out[sbase + row] = 0.f;
        }
    }
}

extern "C" void kernel_launch(void* const* d_in, const int* in_sizes, int n_in,
                              void* d_out, int out_size, void* d_ws, size_t ws_size,
                              hipStream_t stream) {
    const float* deltas  = (const float*)d_in[0];  // [64,31,31,36] f32
    const float* probs   = (const float*)d_in[1];  // [64,31,31,9]  f32
    // d_in[2] = gt_labels (unused)
    const float* anchors = (const float*)d_in[3];  // [8649,4] f32
    float* out = (float*)d_out;                    // 480000 f32
    u64* wskeys = (u64*)d_ws;                      // 64*8704*8 = 4.46 MB

    // opt-in to >64 KB dynamic LDS (gfx950: 160 KB/CU). Host-side attribute,
    // not a stream op -> graph-capture safe; idempotent per call.
    (void)hipFuncSetAttribute((const void*)roibbox_kernel,
                              hipFuncAttributeMaxDynamicSharedMemorySize, DYN_LDS);

    roibbox_kernel<<<dim3(BATCH), dim3(NT), DYN_LDS, stream>>>(
        deltas, probs, anchors, out, wskeys);
}